// Round 10
// baseline (154.413 us; speedup 1.0000x reference)
//
#include <hip/hip_runtime.h>

typedef __bf16 bf16;
typedef bf16 bf16x2 __attribute__((ext_vector_type(2)));
typedef bf16 bf16x4 __attribute__((ext_vector_type(4)));
typedef bf16 bf16x8 __attribute__((ext_vector_type(8)));
typedef float f32x4 __attribute__((ext_vector_type(4)));
typedef float f32x16 __attribute__((ext_vector_type(16)));
typedef int i32x2 __attribute__((ext_vector_type(2)));
typedef int i32x4 __attribute__((ext_vector_type(4)));

#define SEQ 256
#define DH  32
#define VT_PAD 264   // bf16 row stride 528B = 33*16B
#define TRP 36       // tri tile padded cols (floats): 144B row -> bank-spread

// pack two f32 -> one dword of 2 bf16 (v_cvt_pk_bf16_f32)
static __device__ __forceinline__ int pk2(float a, float b) {
    bf16x2 t; t[0] = (bf16)a; t[1] = (bf16)b;
    return __builtin_bit_cast(int, t);
}

static __device__ __forceinline__ bf16x8 cvt8(f32x4 a, f32x4 b) {
    bf16x8 f;
    f[0]=(bf16)a[0]; f[1]=(bf16)a[1]; f[2]=(bf16)a[2]; f[3]=(bf16)a[3];
    f[4]=(bf16)b[0]; f[5]=(bf16)b[1]; f[6]=(bf16)b[2]; f[7]=(bf16)b[3];
    return f;
}

// One C-register group G of the 32x32 QK^T output -> exp2 -> two packed dwords
// covering t = 8G+4hi+{0..3}. All indices compile-time.
template<int G>
static __device__ __forceinline__ i32x2 pgrp(f32x16 cf, f32x4 tg, f32x4 mk, float& lp) {
    constexpr float K1    = 0.17677669529663687f * 1.44269504088896f; // sm_scale*log2e
    constexpr float LOG2E = 1.44269504088896f;
    float p0 = __builtin_amdgcn_exp2f(fmaf(cf[4*G+0], K1, fmaf(tg[0], LOG2E, mk[0])));
    float p1 = __builtin_amdgcn_exp2f(fmaf(cf[4*G+1], K1, fmaf(tg[1], LOG2E, mk[1])));
    float p2 = __builtin_amdgcn_exp2f(fmaf(cf[4*G+2], K1, fmaf(tg[2], LOG2E, mk[2])));
    float p3 = __builtin_amdgcn_exp2f(fmaf(cf[4*G+3], K1, fmaf(tg[3], LOG2E, mk[3])));
    lp += (p0 + p1) + (p2 + p3);
    i32x2 r; r[0] = pk2(p0, p1); r[1] = pk2(p2, p3);
    return r;
}

// 4 permlane32_swap -> two PV A-frags (t-local 0..15 and 16..31)
static __device__ __forceinline__ void frags(i32x2 a0, i32x2 a1, i32x2 a2, i32x2 a3,
                                             bf16x8& f0, bf16x8& f1) {
    i32x2 s0 = __builtin_amdgcn_permlane32_swap(a0[0], a1[0], false, false);
    i32x2 s1 = __builtin_amdgcn_permlane32_swap(a0[1], a1[1], false, false);
    i32x2 s2 = __builtin_amdgcn_permlane32_swap(a2[0], a3[0], false, false);
    i32x2 s3 = __builtin_amdgcn_permlane32_swap(a2[1], a3[1], false, false);
    i32x4 w0 = {s0[0], s1[0], s0[1], s1[1]};
    i32x4 w1 = {s2[0], s3[0], s2[1], s3[1]};
    f0 = __builtin_bit_cast(bf16x8, w0);
    f1 = __builtin_bit_cast(bf16x8, w1);
}

// 32-row stile tri tile loads (coalesced: each instr = 8 rows x 128B dense)
#define LOAD_TRI_A(cc)                                            \
    sA = *(const f32x4*)(tst0 + (cc) * 32 + 0 * 8 * SEQ);         \
    sB = *(const f32x4*)(tst0 + (cc) * 32 + 1 * 8 * SEQ);         \
    sC = *(const f32x4*)(tst0 + (cc) * 32 + 2 * 8 * SEQ);         \
    sD = *(const f32x4*)(tst0 + (cc) * 32 + 3 * 8 * SEQ);

#define LOAD_TRI_B(cc)                                            \
    sE = *(const f32x4*)(tst1 + (cc) * 32 + 0 * 8 * SEQ);         \
    sF = *(const f32x4*)(tst1 + (cc) * 32 + 1 * 8 * SEQ);         \
    sG = *(const f32x4*)(tst1 + (cc) * 32 + 2 * 8 * SEQ);         \
    sH = *(const f32x4*)(tst1 + (cc) * 32 + 3 * 8 * SEQ);

#define STORE_TRI_A()                                             \
    *(f32x4*)(twr + 0 * 8 * TRP) = sA;                            \
    *(f32x4*)(twr + 1 * 8 * TRP) = sB;                            \
    *(f32x4*)(twr + 2 * 8 * TRP) = sC;                            \
    *(f32x4*)(twr + 3 * 8 * TRP) = sD;

#define STORE_TRI_B()                                             \
    *(f32x4*)(twr + 0 * 8 * TRP) = sE;                            \
    *(f32x4*)(twr + 1 * 8 * TRP) = sF;                            \
    *(f32x4*)(twr + 2 * 8 * TRP) = sG;                            \
    *(f32x4*)(twr + 3 * 8 * TRP) = sH;

// S^T = K*Q^T with 32x32x16 MFMAs (M=t keys, N=s queries).
// C layout: col = s = lane&31, row = t = (reg&3) + 8*(reg>>2) + 4*(lane>>5).
// R10: OCCUPANCY UNLOCK. R6/R7/R9 all had 8 waves/CU static (LDS-capped) =
// the measured 18% occupancy ceiling; launch-rate refuted by R9. Fix: LDS
// 75.3 -> 36.4 KB (drop Kb -> K reg-prefetch [R4/R5-validated]; halve Tr to
// one 32-row stile tile, rewritten mid-chunk via same-wave DS ordering) ->
// 4 blocks/CU -> entire 1024-block grid resident (16 waves/CU).
// NOTE: min-waves/EU=2: higher values squeeze VGPRs -> scratch spill
// (R1: 456MB, R3: 235MB, R8: 47MB phantom WRITE_SIZE).
__global__ __launch_bounds__(256, 2) void attn_mfma_kernel(
    const float* __restrict__ q,
    const float* __restrict__ k,
    const float* __restrict__ v,
    const float* __restrict__ mask_bias,   // [N][SEQ]
    const float* __restrict__ tri_bias,    // [H][SEQ][SEQ]
    float* __restrict__ out)
{
    __shared__ __align__(16) bf16  Vt[DH][VT_PAD];  // V^T bf16: 16896 B
    __shared__ __align__(16) float Ml[SEQ];         //            1024 B
    __shared__ __align__(16) float Tr[4][32][TRP];  // tri tile: 18432 B (36.4 KB)

    const int tid  = threadIdx.x;
    const int wave = tid >> 6;
    const int lane = tid & 63;
    const int l31  = lane & 31;
    const int hi   = lane >> 5;

    const int inst = blockIdx.x;       // n*4 + h
    const int n    = inst >> 2;
    const int h    = inst & 3;

    const float* qb = q + (size_t)inst * SEQ * DH;
    const float* kb = k + (size_t)inst * SEQ * DH;
    const float* vb = v + (size_t)inst * SEQ * DH;
    const float* mb = mask_bias + (size_t)n * SEQ;
    const float* tb = tri_bias + (size_t)h * SEQ * SEQ;

    constexpr float LOG2E = 1.44269504088896f;

    const int sbase = wave * 64;       // wave owns 64 queries = 2 stiles of 32

    // coalesced tri staging: lane covers row (stile base)+(lane>>3)+8i, col 4(lane&7)
    const float* tst0 = tb + (size_t)(sbase + (lane >> 3)) * SEQ + (lane & 7) * 4;
    const float* tst1 = tst0 + 32 * SEQ;
    float*       twr  = &Tr[wave][lane >> 3][(lane & 7) * 4];

    f32x4 sA, sB, sC, sD, sE, sF, sG, sH;

    // ---- issue chunk0 stile0 tri loads first (in flight across staging) ----
    LOAD_TRI_A(0);

    // ---- K chunk0 prefetch (scattered 32B segs; R4/R5-validated path) ----
    const float* kp0 = kb + (size_t)l31 * DH + hi * 8;
    f32x4 kA = ((const f32x4*)kp0)[0];
    f32x4 kB = ((const f32x4*)kp0)[1];
    f32x4 kC = ((const f32x4*)(kp0 + 16))[0];
    f32x4 kD = ((const f32x4*)(kp0 + 16))[1];

    // ---- Q b-frags: qfSD = Q[sbase+S*32+l31][D*16 + hi*8 .. +7] ----
    bf16x8 qf00, qf01, qf10, qf11;
    {
        const float* p0 = qb + (size_t)(sbase + l31) * DH + hi * 8;
        const float* p1 = qb + (size_t)(sbase + 32 + l31) * DH + hi * 8;
        qf00 = cvt8(((const f32x4*)p0)[0], ((const f32x4*)p0)[1]);
        qf01 = cvt8(((const f32x4*)(p0 + 16))[0], ((const f32x4*)(p0 + 16))[1]);
        qf10 = cvt8(((const f32x4*)p1)[0], ((const f32x4*)p1)[1]);
        qf11 = cvt8(((const f32x4*)(p1 + 16))[0], ((const f32x4*)(p1 + 16))[1]);
    }

    // ---- stage V^T (bf16) + mask*log2e into LDS (coalesced) ----
    #pragma unroll
    for (int i = 0; i < 8; ++i) {
        int idx = i * 256 + tid;       // float4 index: t = idx>>3, d-group = idx&7
        int t   = idx >> 3;
        int d4  = (idx & 7) * 4;
        f32x4 tv = ((const f32x4*)vb)[idx];
        Vt[d4 + 0][t] = (bf16)tv[0];
        Vt[d4 + 1][t] = (bf16)tv[1];
        Vt[d4 + 2][t] = (bf16)tv[2];
        Vt[d4 + 3][t] = (bf16)tv[3];
    }
    Ml[tid] = mb[tid] * LOG2E;

    // tile <- stile0 chunk0; then start stile1-c0 and stile0-c1 loads
    STORE_TRI_A();
    LOAD_TRI_B(0);
    LOAD_TRI_A(1);

    __syncthreads();                   // for Vt/Ml only

    f32x16 oacc0 = {}, oacc1 = {};
    float lp0 = 0.f, lp1 = 0.f;
    const f32x16 z16 = {};

    // ---- main loop: 8 chunks of 32 keys ----
    // Tile lifecycle per chunk (all same-wave DS ops -> in-order, no barriers):
    //   [tile = S0c] read t -> compute stile0 -> write RB (S1c) -> read u
    //   -> compute stile1 -> write RA (S0,c+1)
    for (int c = 0; c < 8; ++c) {
        const int tb0 = c * 32;

        // tri stile0 chunk c from tile
        const float* trd = &Tr[wave][l31][hi * 4];      // col floats 8g+4hi
        f32x4 t0 = *(const f32x4*)(trd + 0);
        f32x4 t1 = *(const f32x4*)(trd + 8);
        f32x4 t2 = *(const f32x4*)(trd + 16);
        f32x4 t3 = *(const f32x4*)(trd + 24);

        // K frags (prefetched a chunk ago), then reissue next chunk
        bf16x8 kf0 = cvt8(kA, kB);
        bf16x8 kf1 = cvt8(kC, kD);
        if (c < 7) {
            const float* kp = kb + (size_t)(tb0 + 32 + l31) * DH + hi * 8;
            kA = ((const f32x4*)kp)[0];
            kB = ((const f32x4*)kp)[1];
            kC = ((const f32x4*)(kp + 16))[0];
            kD = ((const f32x4*)(kp + 16))[1];
        }

        // V b-frags from LDS (consumed at PV; latency hides under QK+softmax)
        bf16x8 vf0 = *(const bf16x8*)&Vt[l31][tb0 + hi * 8];
        bf16x8 vf1 = *(const bf16x8*)&Vt[l31][tb0 + 16 + hi * 8];

        // mask*log2e (LDS broadcast): t = tb0 + 8g + 4hi + {0..3}
        f32x4 mk0 = *(const f32x4*)&Ml[tb0 +  0 + 4 * hi];
        f32x4 mk1 = *(const f32x4*)&Ml[tb0 +  8 + 4 * hi];
        f32x4 mk2 = *(const f32x4*)&Ml[tb0 + 16 + 4 * hi];
        f32x4 mk3 = *(const f32x4*)&Ml[tb0 + 24 + 4 * hi];

        // ============ stile 0 ============
        __builtin_amdgcn_s_setprio(1);
        f32x16 cf = __builtin_amdgcn_mfma_f32_32x32x16_bf16(kf0, qf00, z16, 0, 0, 0);
        cf = __builtin_amdgcn_mfma_f32_32x32x16_bf16(kf1, qf01, cf, 0, 0, 0);
        __builtin_amdgcn_s_setprio(0);

        i32x2 a0 = pgrp<0>(cf, t0, mk0, lp0);
        i32x2 a1 = pgrp<1>(cf, t1, mk1, lp0);
        i32x2 a2 = pgrp<2>(cf, t2, mk2, lp0);
        i32x2 a3 = pgrp<3>(cf, t3, mk3, lp0);
        bf16x8 pa0, pa1;
        frags(a0, a1, a2, a3, pa0, pa1);

        __builtin_amdgcn_s_setprio(1);
        oacc0 = __builtin_amdgcn_mfma_f32_32x32x16_bf16(pa0, vf0, oacc0, 0, 0, 0);
        oacc0 = __builtin_amdgcn_mfma_f32_32x32x16_bf16(pa1, vf1, oacc0, 0, 0, 0);
        __builtin_amdgcn_s_setprio(0);

        // tile <- stile1 chunk c (RB loaded a chunk ago); refill RB
        STORE_TRI_B();
        if (c < 7) { LOAD_TRI_B(c + 1); }

        // tri stile1 chunk c (reads ordered after the write: same-wave DS)
        f32x4 u0 = *(const f32x4*)(trd + 0);
        f32x4 u1 = *(const f32x4*)(trd + 8);
        f32x4 u2 = *(const f32x4*)(trd + 16);
        f32x4 u3 = *(const f32x4*)(trd + 24);

        // ============ stile 1 ============
        __builtin_amdgcn_s_setprio(1);
        cf = __builtin_amdgcn_mfma_f32_32x32x16_bf16(kf0, qf10, z16, 0, 0, 0);
        cf = __builtin_amdgcn_mfma_f32_32x32x16_bf16(kf1, qf11, cf, 0, 0, 0);
        __builtin_amdgcn_s_setprio(0);

        a0 = pgrp<0>(cf, u0, mk0, lp1);
        a1 = pgrp<1>(cf, u1, mk1, lp1);
        a2 = pgrp<2>(cf, u2, mk2, lp1);
        a3 = pgrp<3>(cf, u3, mk3, lp1);
        bf16x8 pb0, pb1;
        frags(a0, a1, a2, a3, pb0, pb1);

        __builtin_amdgcn_s_setprio(1);
        oacc1 = __builtin_amdgcn_mfma_f32_32x32x16_bf16(pb0, vf0, oacc1, 0, 0, 0);
        oacc1 = __builtin_amdgcn_mfma_f32_32x32x16_bf16(pb1, vf1, oacc1, 0, 0, 0);
        __builtin_amdgcn_s_setprio(0);

        // tile <- stile0 chunk c+1 (RA loaded a chunk ago); refill RA
        if (c < 7) { STORE_TRI_A(); }
        if (c < 6) { LOAD_TRI_A(c + 2); }
    }

    // ---- softmax denominators: hi-half reduce, then normalize + store ----
    lp0 += __shfl_xor(lp0, 32);
    lp1 += __shfl_xor(lp1, 32);
    const float li0 = 1.0f / lp0;      // valid for s = sbase + l31
    const float li1 = 1.0f / lp1;      // valid for s = sbase + 32 + l31

    float* ob = out + (size_t)inst * SEQ * DH;
    #pragma unroll
    for (int r = 0; r < 16; ++r) {
        const int srow = (r & 3) + 8 * (r >> 2) + 4 * hi;
        float i0 = __shfl(li0, srow);  // 1/l for row srow lives in lane srow
        float i1 = __shfl(li1, srow);
        ob[(size_t)(sbase + srow) * DH + l31]      = oacc0[r] * i0;
        ob[(size_t)(sbase + 32 + srow) * DH + l31] = oacc1[r] * i1;
    }
}

extern "C" void kernel_launch(void* const* d_in, const int* in_sizes, int n_in,
                              void* d_out, int out_size, void* d_ws, size_t ws_size,
                              hipStream_t stream) {
    const float* q    = (const float*)d_in[0];
    const float* k    = (const float*)d_in[1];
    const float* v    = (const float*)d_in[2];
    const float* mask = (const float*)d_in[3];
    const float* tri  = (const float*)d_in[4];
    float* out = (float*)d_out;

    attn_mfma_kernel<<<dim3(256 * 4), dim3(256), 0, stream>>>(q, k, v, mask, tri, out);
}

// Round 11
// 148.929 us; speedup vs baseline: 1.0368x; 1.0368x over previous
//
#include <hip/hip_runtime.h>

typedef __bf16 bf16;
typedef bf16 bf16x2 __attribute__((ext_vector_type(2)));
typedef bf16 bf16x4 __attribute__((ext_vector_type(4)));
typedef bf16 bf16x8 __attribute__((ext_vector_type(8)));
typedef float f32x4 __attribute__((ext_vector_type(4)));
typedef float f32x16 __attribute__((ext_vector_type(16)));
typedef int i32x2 __attribute__((ext_vector_type(2)));
typedef int i32x4 __attribute__((ext_vector_type(4)));

#define SEQ 256
#define DH  32
#define VT_PAD 264   // bf16 row stride 528B = 33*16B
#define KB_PAD 40    // bf16 row stride  80B =  5*16B
#define TRP 36       // tri tile padded cols (floats): 144B row -> bank-spread

// pack two f32 -> one dword of 2 bf16 (v_cvt_pk_bf16_f32)
static __device__ __forceinline__ int pk2(float a, float b) {
    bf16x2 t; t[0] = (bf16)a; t[1] = (bf16)b;
    return __builtin_bit_cast(int, t);
}

// One C-register group G of the 32x32 QK^T output -> exp2 -> two packed dwords
// covering t = 8G+4hi+{0..3}. Tile already holds (tri+mask)*log2e, so the
// per-element chain is ONE fma + exp2 (was 2 fma + exp2 through R10).
template<int G>
static __device__ __forceinline__ i32x2 pgrp(f32x16 cf, f32x4 tg, float& lp) {
    constexpr float K1 = 0.17677669529663687f * 1.44269504088896f; // sm_scale*log2e
    float p0 = __builtin_amdgcn_exp2f(fmaf(cf[4*G+0], K1, tg[0]));
    float p1 = __builtin_amdgcn_exp2f(fmaf(cf[4*G+1], K1, tg[1]));
    float p2 = __builtin_amdgcn_exp2f(fmaf(cf[4*G+2], K1, tg[2]));
    float p3 = __builtin_amdgcn_exp2f(fmaf(cf[4*G+3], K1, tg[3]));
    lp += (p0 + p1) + (p2 + p3);
    i32x2 r; r[0] = pk2(p0, p1); r[1] = pk2(p2, p3);
    return r;
}

// 4 permlane32_swap -> two PV A-frags (t-local 0..15 and 16..31)
static __device__ __forceinline__ void frags(i32x2 a0, i32x2 a1, i32x2 a2, i32x2 a3,
                                             bf16x8& f0, bf16x8& f1) {
    i32x2 s0 = __builtin_amdgcn_permlane32_swap(a0[0], a1[0], false, false);
    i32x2 s1 = __builtin_amdgcn_permlane32_swap(a0[1], a1[1], false, false);
    i32x2 s2 = __builtin_amdgcn_permlane32_swap(a2[0], a3[0], false, false);
    i32x2 s3 = __builtin_amdgcn_permlane32_swap(a2[1], a3[1], false, false);
    i32x4 w0 = {s0[0], s1[0], s0[1], s1[1]};
    i32x4 w1 = {s2[0], s3[0], s2[1], s3[1]};
    f0 = __builtin_bit_cast(bf16x8, w0);
    f1 = __builtin_bit_cast(bf16x8, w1);
}

// wave-private tri tile (64 rows x 32 cols, chunk cc) -> 8 named regs + the
// chunk's mask f32x4 (cols (lane&7)*4+{0..3}, broadcast across 8-lane groups).
// Coalesced: instr i covers rows sbase+i*8..+7, each row a dense 128B segment.
#define LOAD_TRI(cc)                                              \
    sA = *(const f32x4*)(tstage + (cc) * 32 + 0 * 8 * SEQ);       \
    sB = *(const f32x4*)(tstage + (cc) * 32 + 1 * 8 * SEQ);       \
    sC = *(const f32x4*)(tstage + (cc) * 32 + 2 * 8 * SEQ);       \
    sD = *(const f32x4*)(tstage + (cc) * 32 + 3 * 8 * SEQ);       \
    sE = *(const f32x4*)(tstage + (cc) * 32 + 4 * 8 * SEQ);       \
    sF = *(const f32x4*)(tstage + (cc) * 32 + 5 * 8 * SEQ);       \
    sG = *(const f32x4*)(tstage + (cc) * 32 + 6 * 8 * SEQ);       \
    sH = *(const f32x4*)(tstage + (cc) * 32 + 7 * 8 * SEQ);       \
    mq = *(const f32x4*)(mstage + (cc) * 32);

// store tile = tri*log2e + mask*log2e (fold both biases off the hot path)
#define STORE_TRI()                                               \
    {                                                             \
        f32x4 mkl;                                                \
        mkl[0] = mq[0] * LOG2E; mkl[1] = mq[1] * LOG2E;           \
        mkl[2] = mq[2] * LOG2E; mkl[3] = mq[3] * LOG2E;           \
        f32x4 w;                                                  \
        w[0]=fmaf(sA[0],LOG2E,mkl[0]); w[1]=fmaf(sA[1],LOG2E,mkl[1]); \
        w[2]=fmaf(sA[2],LOG2E,mkl[2]); w[3]=fmaf(sA[3],LOG2E,mkl[3]); \
        *(f32x4*)(twr + 0 * 8 * TRP) = w;                         \
        w[0]=fmaf(sB[0],LOG2E,mkl[0]); w[1]=fmaf(sB[1],LOG2E,mkl[1]); \
        w[2]=fmaf(sB[2],LOG2E,mkl[2]); w[3]=fmaf(sB[3],LOG2E,mkl[3]); \
        *(f32x4*)(twr + 1 * 8 * TRP) = w;                         \
        w[0]=fmaf(sC[0],LOG2E,mkl[0]); w[1]=fmaf(sC[1],LOG2E,mkl[1]); \
        w[2]=fmaf(sC[2],LOG2E,mkl[2]); w[3]=fmaf(sC[3],LOG2E,mkl[3]); \
        *(f32x4*)(twr + 2 * 8 * TRP) = w;                         \
        w[0]=fmaf(sD[0],LOG2E,mkl[0]); w[1]=fmaf(sD[1],LOG2E,mkl[1]); \
        w[2]=fmaf(sD[2],LOG2E,mkl[2]); w[3]=fmaf(sD[3],LOG2E,mkl[3]); \
        *(f32x4*)(twr + 3 * 8 * TRP) = w;                         \
        w[0]=fmaf(sE[0],LOG2E,mkl[0]); w[1]=fmaf(sE[1],LOG2E,mkl[1]); \
        w[2]=fmaf(sE[2],LOG2E,mkl[2]); w[3]=fmaf(sE[3],LOG2E,mkl[3]); \
        *(f32x4*)(twr + 4 * 8 * TRP) = w;                         \
        w[0]=fmaf(sF[0],LOG2E,mkl[0]); w[1]=fmaf(sF[1],LOG2E,mkl[1]); \
        w[2]=fmaf(sF[2],LOG2E,mkl[2]); w[3]=fmaf(sF[3],LOG2E,mkl[3]); \
        *(f32x4*)(twr + 5 * 8 * TRP) = w;                         \
        w[0]=fmaf(sG[0],LOG2E,mkl[0]); w[1]=fmaf(sG[1],LOG2E,mkl[1]); \
        w[2]=fmaf(sG[2],LOG2E,mkl[2]); w[3]=fmaf(sG[3],LOG2E,mkl[3]); \
        *(f32x4*)(twr + 6 * 8 * TRP) = w;                         \
        w[0]=fmaf(sH[0],LOG2E,mkl[0]); w[1]=fmaf(sH[1],LOG2E,mkl[1]); \
        w[2]=fmaf(sH[2],LOG2E,mkl[2]); w[3]=fmaf(sH[3],LOG2E,mkl[3]); \
        *(f32x4*)(twr + 7 * 8 * TRP) = w;                         \
    }

// S^T = K*Q^T with 32x32x16 MFMAs (M=t keys, N=s queries).
// C layout: col = s = lane&31, row = t = (reg&3) + 8*(reg>>2) + 4*(lane>>5).
// R11 = R6 base (best measured, 51.1us) + two decontaminations:
//  1. ALL s_setprio removed (added R5 which regressed 65->68.6; m190-negative
//     on lockstep structures; contaminated every round since).
//  2. Biases pre-folded into the tri tile at STORE time; Ml + in-loop mk
//     reads deleted; softmax chain = 1 fma + exp2 per element.
// Occupancy/launch/TLP theories all refuted (R7/R9/R10 nulls) -> this tests
// the per-wave-chain + arbitration residue. If flat, R12 = in-block key-split.
// NOTE: min-waves/EU=2: higher values squeeze VGPRs -> scratch spill
// (R1: 456MB, R3: 235MB, R8: 47MB phantom WRITE_SIZE).
__global__ __launch_bounds__(256, 2) void attn_mfma_kernel(
    const float* __restrict__ q,
    const float* __restrict__ k,
    const float* __restrict__ v,
    const float* __restrict__ mask_bias,   // [N][SEQ]
    const float* __restrict__ tri_bias,    // [H][SEQ][SEQ]
    float* __restrict__ out)
{
    __shared__ __align__(16) bf16  Vt[DH][VT_PAD];   // V^T bf16: 16896 B
    __shared__ __align__(16) bf16  Kb[SEQ][KB_PAD];  // K bf16:   20480 B
    __shared__ __align__(16) float Tr[4][64][TRP];   // tri tiles: 36864 B (74.2 KB)

    const int tid  = threadIdx.x;
    const int wave = tid >> 6;
    const int lane = tid & 63;
    const int l31  = lane & 31;
    const int hi   = lane >> 5;

    const int inst = blockIdx.x;       // n*4 + h
    const int n    = inst >> 2;
    const int h    = inst & 3;

    const float* qb = q + (size_t)inst * SEQ * DH;
    const float* kb = k + (size_t)inst * SEQ * DH;
    const float* vb = v + (size_t)inst * SEQ * DH;
    const float* mb = mask_bias + (size_t)n * SEQ;
    const float* tb = tri_bias + (size_t)h * SEQ * SEQ;

    constexpr float LOG2E = 1.44269504088896f;

    const int sbase = wave * 64;       // wave owns 64 queries = 2 stiles of 32

    // coalesced tri staging: lane covers row sbase+(lane>>3)+8i, 16B col (lane&7)
    const float* tstage = tb + (size_t)(sbase + (lane >> 3)) * SEQ + (lane & 7) * 4;
    const float* mstage = mb + (lane & 7) * 4;
    float*       twr    = &Tr[wave][lane >> 3][(lane & 7) * 4];

    f32x4 sA, sB, sC, sD, sE, sF, sG, sH, mq;

    // ---- issue chunk0 tri+mask loads first (in flight across all staging) ----
    LOAD_TRI(0);

    // ---- Q b-frags: qfSD = Q[sbase+S*32+l31][D*16 + hi*8 .. +7] ----
    bf16x8 qf00, qf01, qf10, qf11;
    {
        const float* p0 = qb + (size_t)(sbase + l31) * DH + hi * 8;
        const float* p1 = qb + (size_t)(sbase + 32 + l31) * DH + hi * 8;
        f32x4 a, b;
        bf16x8 f;
        a = ((const f32x4*)p0)[0]; b = ((const f32x4*)p0)[1];
        f[0]=(bf16)a[0]; f[1]=(bf16)a[1]; f[2]=(bf16)a[2]; f[3]=(bf16)a[3];
        f[4]=(bf16)b[0]; f[5]=(bf16)b[1]; f[6]=(bf16)b[2]; f[7]=(bf16)b[3];
        qf00 = f;
        a = ((const f32x4*)(p0 + 16))[0]; b = ((const f32x4*)(p0 + 16))[1];
        f[0]=(bf16)a[0]; f[1]=(bf16)a[1]; f[2]=(bf16)a[2]; f[3]=(bf16)a[3];
        f[4]=(bf16)b[0]; f[5]=(bf16)b[1]; f[6]=(bf16)b[2]; f[7]=(bf16)b[3];
        qf01 = f;
        a = ((const f32x4*)p1)[0]; b = ((const f32x4*)p1)[1];
        f[0]=(bf16)a[0]; f[1]=(bf16)a[1]; f[2]=(bf16)a[2]; f[3]=(bf16)a[3];
        f[4]=(bf16)b[0]; f[5]=(bf16)b[1]; f[6]=(bf16)b[2]; f[7]=(bf16)b[3];
        qf10 = f;
        a = ((const f32x4*)(p1 + 16))[0]; b = ((const f32x4*)(p1 + 16))[1];
        f[0]=(bf16)a[0]; f[1]=(bf16)a[1]; f[2]=(bf16)a[2]; f[3]=(bf16)a[3];
        f[4]=(bf16)b[0]; f[5]=(bf16)b[1]; f[6]=(bf16)b[2]; f[7]=(bf16)b[3];
        qf11 = f;
    }

    // ---- stage V^T (bf16) + K (bf16) into LDS (coalesced) ----
    #pragma unroll
    for (int i = 0; i < 8; ++i) {
        int idx = i * 256 + tid;       // float4 index: t = idx>>3, d-group = idx&7
        int t   = idx >> 3;
        int d4  = (idx & 7) * 4;
        f32x4 tv = ((const f32x4*)vb)[idx];
        Vt[d4 + 0][t] = (bf16)tv[0];
        Vt[d4 + 1][t] = (bf16)tv[1];
        Vt[d4 + 2][t] = (bf16)tv[2];
        Vt[d4 + 3][t] = (bf16)tv[3];
        f32x4 tk = ((const f32x4*)kb)[idx];
        bf16x4 kk;
        kk[0]=(bf16)tk[0]; kk[1]=(bf16)tk[1]; kk[2]=(bf16)tk[2]; kk[3]=(bf16)tk[3];
        *(bf16x4*)&Kb[t][d4] = kk;
    }

    // write tri chunk0 tile (biases folded), then start chunk1 loads
    STORE_TRI();
    LOAD_TRI(1);

    __syncthreads();                   // for Vt/Kb only

    f32x16 oacc0 = {}, oacc1 = {};
    float lp0a = 0.f, lp0b = 0.f, lp1a = 0.f, lp1b = 0.f;
    const f32x16 z16 = {};

    // ---- main loop: 8 chunks of 32 keys ----
    for (int c = 0; c < 8; ++c) {
        const int tb0 = c * 32;

        // tri(+biases) for chunk c from wave-private LDS tile
        const float* trd = &Tr[wave][l31][hi * 4];      // col floats 8g+4hi
        f32x4 t0 = *(const f32x4*)(trd + 0);
        f32x4 t1 = *(const f32x4*)(trd + 8);
        f32x4 t2 = *(const f32x4*)(trd + 16);
        f32x4 t3 = *(const f32x4*)(trd + 24);
        f32x4 u0 = *(const f32x4*)(trd + 32 * TRP + 0);
        f32x4 u1 = *(const f32x4*)(trd + 32 * TRP + 8);
        f32x4 u2 = *(const f32x4*)(trd + 32 * TRP + 16);
        f32x4 u3 = *(const f32x4*)(trd + 32 * TRP + 24);

        // K a-frags + V b-frags from LDS
        bf16x8 kf0 = *(const bf16x8*)&Kb[tb0 + l31][hi * 8];
        bf16x8 kf1 = *(const bf16x8*)&Kb[tb0 + l31][16 + hi * 8];
        bf16x8 vf0 = *(const bf16x8*)&Vt[l31][tb0 + hi * 8];
        bf16x8 vf1 = *(const bf16x8*)&Vt[l31][tb0 + 16 + hi * 8];

        // ============ stile 0 ============
        f32x16 cf = __builtin_amdgcn_mfma_f32_32x32x16_bf16(kf0, qf00, z16, 0, 0, 0);
        cf = __builtin_amdgcn_mfma_f32_32x32x16_bf16(kf1, qf01, cf, 0, 0, 0);

        i32x2 a0 = pgrp<0>(cf, t0, lp0a);
        i32x2 a1 = pgrp<1>(cf, t1, lp0b);
        i32x2 a2 = pgrp<2>(cf, t2, lp0a);
        i32x2 a3 = pgrp<3>(cf, t3, lp0b);
        bf16x8 pa0, pa1;
        frags(a0, a1, a2, a3, pa0, pa1);

        oacc0 = __builtin_amdgcn_mfma_f32_32x32x16_bf16(pa0, vf0, oacc0, 0, 0, 0);
        oacc0 = __builtin_amdgcn_mfma_f32_32x32x16_bf16(pa1, vf1, oacc0, 0, 0, 0);

        // tile maintenance: write chunk c+1 (regs loaded last iter), start c+2.
        // Safe vs the t/u reads above: same-wave DS ops execute in order.
        if (c < 7) { STORE_TRI(); }
        if (c < 6) { LOAD_TRI(c + 2); }

        // ============ stile 1 ============
        cf = __builtin_amdgcn_mfma_f32_32x32x16_bf16(kf0, qf10, z16, 0, 0, 0);
        cf = __builtin_amdgcn_mfma_f32_32x32x16_bf16(kf1, qf11, cf, 0, 0, 0);

        a0 = pgrp<0>(cf, u0, lp1a);
        a1 = pgrp<1>(cf, u1, lp1b);
        a2 = pgrp<2>(cf, u2, lp1a);
        a3 = pgrp<3>(cf, u3, lp1b);
        bf16x8 pb0, pb1;
        frags(a0, a1, a2, a3, pb0, pb1);

        oacc1 = __builtin_amdgcn_mfma_f32_32x32x16_bf16(pb0, vf0, oacc1, 0, 0, 0);
        oacc1 = __builtin_amdgcn_mfma_f32_32x32x16_bf16(pb1, vf1, oacc1, 0, 0, 0);
    }

    // ---- softmax denominators: hi-half reduce, then normalize + store ----
    float lp0 = lp0a + lp0b;
    float lp1 = lp1a + lp1b;
    lp0 += __shfl_xor(lp0, 32);
    lp1 += __shfl_xor(lp1, 32);
    const float li0 = 1.0f / lp0;      // valid for s = sbase + l31
    const float li1 = 1.0f / lp1;      // valid for s = sbase + 32 + l31

    float* ob = out + (size_t)inst * SEQ * DH;
    #pragma unroll
    for (int r = 0; r < 16; ++r) {
        const int srow = (r & 3) + 8 * (r >> 2) + 4 * hi;
        float i0 = __shfl(li0, srow);  // 1/l for row srow lives in lane srow
        float i1 = __shfl(li1, srow);
        ob[(size_t)(sbase + srow) * DH + l31]      = oacc0[r] * i0;
        ob[(size_t)(sbase + 32 + srow) * DH + l31] = oacc1[r] * i1;
    }
}

extern "C" void kernel_launch(void* const* d_in, const int* in_sizes, int n_in,
                              void* d_out, int out_size, void* d_ws, size_t ws_size,
                              hipStream_t stream) {
    const float* q    = (const float*)d_in[0];
    const float* k    = (const float*)d_in[1];
    const float* v    = (const float*)d_in[2];
    const float* mask = (const float*)d_in[3];
    const float* tri  = (const float*)d_in[4];
    float* out = (float*)d_out;

    attn_mfma_kernel<<<dim3(256 * 4), dim3(256), 0, stream>>>(q, k, v, mask, tri, out);
}